// Round 4
// baseline (2011.552 us; speedup 1.0000x reference)
//
#include <hip/hip_runtime.h>
#include <math.h>

// B=8, S=2048, N=16384 tokens, D=1024, H=16, HD=64, E=64, K(topk)=2
// fp32-accurate fp16-split GEMM: a = a1 + a2/4096 (a1=fp16(a), a2'=fp16((a-a1)*4096))
// C = a1b1 + (a1*b2' + a2'*b1)/4096  (drops a2b2 ~ 2^-22 relative)

typedef _Float16 h8 __attribute__((ext_vector_type(8)));
typedef _Float16 h4 __attribute__((ext_vector_type(4)));
typedef float f4 __attribute__((ext_vector_type(4)));

// global -> LDS direct copy, 16B per lane. LDS dest is wave-uniform base +
// lane*16; passing per-lane (tid-linear) lds ptr satisfies that contract.
#define GLOAD16(g, l) __builtin_amdgcn_global_load_lds( \
    (const __attribute__((address_space(1))) unsigned int*)(g), \
    (__attribute__((address_space(3))) unsigned int*)(l), 16, 0, 0)

__device__ __forceinline__ float gelu_exact(float x) {
    return 0.5f * x * (1.0f + erff(x * 0.70710678118654752f));
}

// ---------------------------------------------------------------------------
// split2: fp32 (rows x cols) -> fp16 (rows x 2*cols): [v1 | (v-v1)*4096]
// cols = 1<<colsh
// ---------------------------------------------------------------------------
__global__ __launch_bounds__(256) void split2_kernel(
    const float* __restrict__ src, _Float16* __restrict__ dst, long total, int colsh) {
    long i = ((long)blockIdx.x * 256 + threadIdx.x) * 4;
    if (i >= total) return;
    f4 v = *(const f4*)(src + i);
    long row = i >> colsh; int col = (int)(i & ((1 << colsh) - 1));
    _Float16* d0 = dst + (row << (colsh + 1)) + col;
    h4 lo, hi;
    #pragma unroll
    for (int j = 0; j < 4; j++) {
        _Float16 a = (_Float16)v[j];
        lo[j] = a;
        hi[j] = (_Float16)((v[j] - (float)a) * 4096.0f);
    }
    *(h4*)d0 = lo;
    *(h4*)(d0 + (1 << colsh)) = hi;
}

// ---------------------------------------------------------------------------
// K1: k/v projections of expert embeddings (fp32, tiny).
// K layout [h][e][hd]; V stored TRANSPOSED [h][hd][e].
// ---------------------------------------------------------------------------
__global__ __launch_bounds__(256) void kv_kernel(
    const float* __restrict__ w, const float* __restrict__ b,
    const float* __restrict__ ee, float* __restrict__ kbuf, float* __restrict__ vtbuf) {
    __shared__ float As[32][68];
    __shared__ float Bs[32][68];
    int tid = threadIdx.x;
    int r0 = blockIdx.x * 64;
    int tx = tid & 15, ty = tid >> 4;
    float acc[4][4] = {};
    const float* wbase = w + (size_t)(1024 + r0) * 1024;
    for (int k0 = 0; k0 < 1024; k0 += 32) {
        #pragma unroll
        for (int i = 0; i < 2; i++) {
            int f = tid + i * 256;
            int row = f >> 3, c4 = f & 7;
            float4 v = *(const float4*)(wbase + (size_t)row * 1024 + k0 + c4 * 4);
            As[c4*4+0][row] = v.x; As[c4*4+1][row] = v.y;
            As[c4*4+2][row] = v.z; As[c4*4+3][row] = v.w;
            float4 u = *(const float4*)(ee + (size_t)row * 1024 + k0 + c4 * 4);
            Bs[c4*4+0][row] = u.x; Bs[c4*4+1][row] = u.y;
            Bs[c4*4+2][row] = u.z; Bs[c4*4+3][row] = u.w;
        }
        __syncthreads();
        #pragma unroll
        for (int kk = 0; kk < 32; kk++) {
            float a[4], bb[4];
            *(float4*)&a[0]  = *(const float4*)&As[kk][ty * 4];
            *(float4*)&bb[0] = *(const float4*)&Bs[kk][tx * 4];
            #pragma unroll
            for (int i = 0; i < 4; i++)
                #pragma unroll
                for (int j = 0; j < 4; j++)
                    acc[i][j] = fmaf(a[i], bb[j], acc[i][j]);
        }
        __syncthreads();
    }
    #pragma unroll
    for (int i = 0; i < 4; i++) {
        int row = r0 + ty * 4 + i;
        float bias = b[1024 + row];
        int j = row & 1023;
        int h = j >> 6, hd = j & 63;
        #pragma unroll
        for (int jj = 0; jj < 4; jj++) {
            int e = tx * 4 + jj;
            float val = acc[i][jj] + bias;
            if (row < 1024) kbuf[h * 4096 + e * 64 + hd] = val;
            else            vtbuf[h * 4096 + hd * 64 + e] = val;
        }
    }
}

// ---------------------------------------------------------------------------
// hgemm: C[M x N] = A_split(M x 2048) x B_split(N x 2048)^T + bias (+GELU)
// fp16 MFMA 16x16x32, 128x128 tile, 256 thr (2x2 waves of 64x64), BK=32.
// m97 structure: global_load_lds 16B staging, linear LDS, 2-barrier K-step.
// OSPLIT: write fp16 split pair (lo at n, hi at nhalf+n) instead of fp32.
// ---------------------------------------------------------------------------
template<int GELU, int OSPLIT>
__global__ __launch_bounds__(256, 4) void hgemm_kernel(
    const _Float16* __restrict__ A, const _Float16* __restrict__ B,
    const float* __restrict__ bias, void* __restrict__ Cv, int ldc, int nhalf) {
    __shared__ __align__(16) _Float16 As[128 * 32];
    __shared__ __align__(16) _Float16 Bl[128 * 32];
    __shared__ __align__(16) _Float16 Bh[128 * 32];
    int tid = threadIdx.x;
    int m0 = blockIdx.y * 128, n0 = blockIdx.x * 128;
    int w = tid >> 6, l = tid & 63;
    int wm = w & 1, wn = w >> 1;
    int lr = l & 15, lk = l >> 4;

    f4 acc1[4][4], acc2[4][4];
    #pragma unroll
    for (int i = 0; i < 4; i++)
        #pragma unroll
        for (int j = 0; j < 4; j++) {
            acc1[i][j] = (f4){0.f, 0.f, 0.f, 0.f};
            acc2[i][j] = (f4){0.f, 0.f, 0.f, 0.f};
        }

    int r0 = tid >> 2, c0 = (tid & 3) * 8;          // 16B chunk per lane
    int r1 = r0 + 64;                                // second chunk (tid+256)
    const _Float16* Ab = A + (size_t)m0 * 2048;
    const _Float16* Bb = B + (size_t)n0 * 2048;
    _Float16* As0 = As + tid * 8;  _Float16* As1 = As + (tid + 256) * 8;
    _Float16* Bl0 = Bl + tid * 8;  _Float16* Bl1 = Bl + (tid + 256) * 8;
    _Float16* Bh0 = Bh + tid * 8;  _Float16* Bh1 = Bh + (tid + 256) * 8;

    // ---- phase 1: k in [0,1024): acc1 += a1*b1; acc2 += a1*b2' ----
    for (int kt = 0; kt < 32; kt++) {
        int ka = kt * 32;
        __syncthreads();
        GLOAD16(Ab + (size_t)r0 * 2048 + ka + c0, As0);
        GLOAD16(Ab + (size_t)r1 * 2048 + ka + c0, As1);
        GLOAD16(Bb + (size_t)r0 * 2048 + ka + c0, Bl0);
        GLOAD16(Bb + (size_t)r1 * 2048 + ka + c0, Bl1);
        GLOAD16(Bb + (size_t)r0 * 2048 + 1024 + ka + c0, Bh0);
        GLOAD16(Bb + (size_t)r1 * 2048 + 1024 + ka + c0, Bh1);
        __syncthreads();
        h8 af[4], blf[4], bhf[4];
        #pragma unroll
        for (int mi = 0; mi < 4; mi++)
            af[mi] = *(const h8*)(As + (wm * 64 + mi * 16 + lr) * 32 + lk * 8);
        #pragma unroll
        for (int ni = 0; ni < 4; ni++) {
            blf[ni] = *(const h8*)(Bl + (wn * 64 + ni * 16 + lr) * 32 + lk * 8);
            bhf[ni] = *(const h8*)(Bh + (wn * 64 + ni * 16 + lr) * 32 + lk * 8);
        }
        #pragma unroll
        for (int mi = 0; mi < 4; mi++)
            #pragma unroll
            for (int ni = 0; ni < 4; ni++) {
                acc1[mi][ni] = __builtin_amdgcn_mfma_f32_16x16x32_f16(af[mi], blf[ni], acc1[mi][ni], 0, 0, 0);
                acc2[mi][ni] = __builtin_amdgcn_mfma_f32_16x16x32_f16(af[mi], bhf[ni], acc2[mi][ni], 0, 0, 0);
            }
    }

    // ---- phase 2: k in [1024,2048): acc2 += a2'*b1 ----
    for (int kt = 0; kt < 32; kt++) {
        int ka = kt * 32;
        __syncthreads();
        GLOAD16(Ab + (size_t)r0 * 2048 + 1024 + ka + c0, As0);
        GLOAD16(Ab + (size_t)r1 * 2048 + 1024 + ka + c0, As1);
        GLOAD16(Bb + (size_t)r0 * 2048 + ka + c0, Bh0);
        GLOAD16(Bb + (size_t)r1 * 2048 + ka + c0, Bh1);
        __syncthreads();
        h8 af[4], bhf[4];
        #pragma unroll
        for (int mi = 0; mi < 4; mi++)
            af[mi] = *(const h8*)(As + (wm * 64 + mi * 16 + lr) * 32 + lk * 8);
        #pragma unroll
        for (int ni = 0; ni < 4; ni++)
            bhf[ni] = *(const h8*)(Bh + (wn * 64 + ni * 16 + lr) * 32 + lk * 8);
        #pragma unroll
        for (int mi = 0; mi < 4; mi++)
            #pragma unroll
            for (int ni = 0; ni < 4; ni++)
                acc2[mi][ni] = __builtin_amdgcn_mfma_f32_16x16x32_f16(af[mi], bhf[ni], acc2[mi][ni], 0, 0, 0);
    }

    // ---- epilogue: C/D layout col=lane&15, row=(lane>>4)*4+reg ----
    #pragma unroll
    for (int mi = 0; mi < 4; mi++)
        #pragma unroll
        for (int ni = 0; ni < 4; ni++) {
            int n = n0 + wn * 64 + ni * 16 + lr;
            float bn = bias[n];
            #pragma unroll
            for (int j = 0; j < 4; j++) {
                int m = m0 + wm * 64 + mi * 16 + lk * 4 + j;
                float val = acc1[mi][ni][j] + acc2[mi][ni][j] * (1.0f / 4096.0f) + bn;
                if (GELU) val = gelu_exact(val);
                if (OSPLIT) {
                    _Float16* Ch = (_Float16*)Cv;
                    _Float16 lo = (_Float16)val;
                    Ch[(size_t)m * ldc + n] = lo;
                    Ch[(size_t)m * ldc + nhalf + n] = (_Float16)((val - (float)lo) * 4096.0f);
                } else {
                    ((float*)Cv)[(size_t)m * ldc + n] = val;
                }
            }
        }
}

// ---------------------------------------------------------------------------
// attn2: wave-autonomous cross-attention. Each wave: one (b,h,64-token tile).
// lane = expert (scores) AND lane = hd (PV). K rows / V^T rows in registers.
// Writes O directly as fp16 split into os (M x 2048).
// ---------------------------------------------------------------------------
__global__ __launch_bounds__(256) void attn2_kernel(
    const float* __restrict__ kbuf, const float* __restrict__ vtbuf,
    const float* __restrict__ q, _Float16* __restrict__ os) {
    __shared__ __align__(16) float qs[4][64][68];
    __shared__ __align__(16) float ps[4][2][64];
    int tid = threadIdx.x;
    int w = tid >> 6, l = tid & 63;
    int wid = blockIdx.x * 4 + w;
    int b = wid >> 9, h = (wid >> 5) & 15, t0 = (wid & 31) * 64;

    f4 kr[16], vt[16];
    const f4* kp = (const f4*)(kbuf + h * 4096 + l * 64);
    const f4* vp = (const f4*)(vtbuf + h * 4096 + l * 64);
    #pragma unroll
    for (int i = 0; i < 16; i++) { kr[i] = kp[i]; vt[i] = vp[i]; }

    const float* qbase = q + ((size_t)(b * 2048 + t0)) * 1024 + h * 64;
    #pragma unroll
    for (int it = 0; it < 16; it++) {
        int f = it * 64 + l;
        int r = f >> 4, c = f & 15;
        f4 v = *(const f4*)(qbase + (size_t)r * 1024 + c * 4);
        *(f4*)&qs[w][r][c * 4] = v;
    }

    for (int t = 0; t < 64; t++) {
        float s = 0.f;
        #pragma unroll
        for (int i = 0; i < 16; i++) {
            f4 qv = *(const f4*)&qs[w][t][i * 4];
            s = fmaf(qv[0], kr[i][0], s);
            s = fmaf(qv[1], kr[i][1], s);
            s = fmaf(qv[2], kr[i][2], s);
            s = fmaf(qv[3], kr[i][3], s);
        }
        s *= 0.125f;
        float ex = __expf(s);
        float sum = ex;
        #pragma unroll
        for (int off = 32; off; off >>= 1) sum += __shfl_xor(sum, off, 64);
        float p = ex / sum;
        ps[w][t & 1][l] = p;
        float o = 0.f;
        #pragma unroll
        for (int i = 0; i < 16; i++) {
            f4 pv = *(const f4*)&ps[w][t & 1][i * 4];
            o = fmaf(pv[0], vt[i][0], o);
            o = fmaf(pv[1], vt[i][1], o);
            o = fmaf(pv[2], vt[i][2], o);
            o = fmaf(pv[3], vt[i][3], o);
        }
        _Float16 o1 = (_Float16)o;
        _Float16 o2 = (_Float16)((o - (float)o1) * 4096.0f);
        size_t tok = (size_t)(b * 2048 + t0 + t);
        os[tok * 2048 + h * 64 + l] = o1;
        os[tok * 2048 + 1024 + h * 64 + l] = o2;
    }
}

// ---------------------------------------------------------------------------
// gate2: logits(16384x64) = h1s(16384x[256|256]) @ gw2s(64x[256|256])^T + b2
// via 4-product split MFMA (frags straight from global/L2), then fused
// softmax + top-2 + weight normalization. Wave handles 16 tokens.
// ---------------------------------------------------------------------------
__global__ __launch_bounds__(256) void gate2_kernel(
    const _Float16* __restrict__ h1s, const _Float16* __restrict__ w2s,
    const float* __restrict__ b2, float* __restrict__ out) {
    int tid = threadIdx.x;
    int w = tid >> 6, l = tid & 63;
    int lr = l & 15, lk = l >> 4;
    int trow = blockIdx.x * 64 + w * 16;        // wave's 16 tokens

    f4 acc1[4], acc2[4], acc3[4];
    #pragma unroll
    for (int ni = 0; ni < 4; ni++) {
        acc1[ni] = (f4){0.f,0.f,0.f,0.f};
        acc2[ni] = (f4){0.f,0.f,0.f,0.f};
        acc3[ni] = (f4){0.f,0.f,0.f,0.f};
    }
    const _Float16* Arow = h1s + (size_t)(trow + lr) * 512;
    #pragma unroll
    for (int kt = 0; kt < 8; kt++) {
        h8 a1 = *(const h8*)(Arow + kt * 32 + lk * 8);
        h8 a2 = *(const h8*)(Arow + 256 + kt * 32 + lk * 8);
        #pragma unroll
        for (int ni = 0; ni < 4; ni++) {
            const _Float16* Brow = w2s + (size_t)(ni * 16 + lr) * 512;
            h8 b1 = *(const h8*)(Brow + kt * 32 + lk * 8);
            h8 bh = *(const h8*)(Brow + 256 + kt * 32 + lk * 8);
            acc1[ni] = __builtin_amdgcn_mfma_f32_16x16x32_f16(a1, b1, acc1[ni], 0, 0, 0);
            acc2[ni] = __builtin_amdgcn_mfma_f32_16x16x32_f16(a1, bh, acc2[ni], 0, 0, 0);
            acc2[ni] = __builtin_amdgcn_mfma_f32_16x16x32_f16(a2, b1, acc2[ni], 0, 0, 0);
            acc3[ni] = __builtin_amdgcn_mfma_f32_16x16x32_f16(a2, bh, acc3[ni], 0, 0, 0);
        }
    }
    float bcol[4];
    #pragma unroll
    for (int ni = 0; ni < 4; ni++) bcol[ni] = b2[ni * 16 + lr];

    const float c1 = 1.0f / 4096.0f, c2 = 1.0f / 16777216.0f;
    #pragma unroll
    for (int j = 0; j < 4; j++) {
        int tok = trow + lk * 4 + j;
        float lg[4];
        #pragma unroll
        for (int ni = 0; ni < 4; ni++)
            lg[ni] = acc1[ni][j] + acc2[ni][j] * c1 + acc3[ni][j] * c2 + bcol[ni];
        float mx = fmaxf(fmaxf(lg[0], lg[1]), fmaxf(lg[2], lg[3]));
        #pragma unroll
        for (int off = 1; off <= 8; off <<= 1) mx = fmaxf(mx, __shfl_xor(mx, off, 64));
        float pr[4], s = 0.f;
        #pragma unroll
        for (int ni = 0; ni < 4; ni++) { pr[ni] = expf(lg[ni] - mx); s += pr[ni]; }
        #pragma unroll
        for (int off = 1; off <= 8; off <<= 1) s += __shfl_xor(s, off, 64);
        float inv = 1.0f / s;
        float v1 = -1.f, v2 = -1.f; int i1 = 0, i2 = 0;
        #pragma unroll
        for (int ni = 0; ni < 4; ni++) {
            float p = pr[ni] * inv;
            int e = ni * 16 + lr;
            if (p > v1) { v2 = v1; i2 = i1; v1 = p; i1 = e; }
            else if (p > v2) { v2 = p; i2 = e; }
        }
        #pragma unroll
        for (int off = 1; off <= 8; off <<= 1) {
            float u1 = __shfl_xor(v1, off, 64); int k1 = __shfl_xor(i1, off, 64);
            float u2 = __shfl_xor(v2, off, 64); int k2 = __shfl_xor(i2, off, 64);
            if (u1 > v1) {
                if (v1 > u2) { v2 = v1; i2 = i1; } else { v2 = u2; i2 = k2; }
                v1 = u1; i1 = k1;
            } else if (u1 > v2) { v2 = u1; i2 = k1; }
        }
        if (lr == 0) {
            float wsum = v1 + v2 + 1e-8f;
            out[(size_t)tok * 2]     = (float)i1;
            out[(size_t)tok * 2 + 1] = (float)i2;
            out[32768 + (size_t)tok * 2]     = v1 / wsum;
            out[32768 + (size_t)tok * 2 + 1] = v2 / wsum;
        }
    }
}

// ---------------------------------------------------------------------------
extern "C" void kernel_launch(void* const* d_in, const int* in_sizes, int n_in,
                              void* d_out, int out_size, void* d_ws, size_t ws_size,
                              hipStream_t stream) {
    const float* x   = (const float*)d_in[0];
    const float* ee  = (const float*)d_in[1];
    const float* ipw = (const float*)d_in[2];
    const float* ipb = (const float*)d_in[3];
    const float* opw = (const float*)d_in[4];
    const float* opb = (const float*)d_in[5];
    const float* gw1 = (const float*)d_in[6];
    const float* gb1 = (const float*)d_in[7];
    const float* gw2 = (const float*)d_in[8];
    const float* gb2 = (const float*)d_in[9];
    float* out = (float*)d_out;
    char* ws = (char*)d_ws;

    // region1 (64MB): xs (x-split) -> os (O-split) -> h1s (h1-split, 16MB)
    _Float16* xs    = (_Float16*)ws;                          // 16384 x 2048 fp16
    _Float16* h1s   = (_Float16*)ws;                          // 16384 x 512 fp16 (alias)
    // region2 (64MB): qbuf (Q fp32) -> aos (attn_out split fp16)
    float*    qbuf  = (float*)(ws + 67108864);                // 16384 x 1024 f32
    _Float16* aos   = (_Float16*)(ws + 67108864);             // 16384 x 2048 fp16 (alias)
    _Float16* wqs   = (_Float16*)(ws + 134217728);            // 1024 x 2048
    _Float16* opws  = (_Float16*)(ws + 138412032);            // 1024 x 2048
    _Float16* gw1s  = (_Float16*)(ws + 142606336);            // 256 x 2048
    float*    kbuf  = (float*)(ws + 143654912);               // 16x64x64 f32
    _Float16* gw2s  = (_Float16*)(ws + 143654912);            // 64 x 512 (aliases kbuf, used after attn)
    float*    vtbuf = (float*)(ws + 143917056);               // 16x64x64 f32 (transposed)

    split2_kernel<<<dim3(1024),  dim3(256), 0, stream>>>(ipw, wqs, 1048576L, 10);
    split2_kernel<<<dim3(1024),  dim3(256), 0, stream>>>(opw, opws, 1048576L, 10);
    split2_kernel<<<dim3(256),   dim3(256), 0, stream>>>(gw1, gw1s, 262144L, 10);
    split2_kernel<<<dim3(16384), dim3(256), 0, stream>>>(x, xs, 16777216L, 10);
    kv_kernel<<<dim3(32), dim3(256), 0, stream>>>(ipw, ipb, ee, kbuf, vtbuf);
    // Q = x @ wq^T + bq (fp32 out)
    hgemm_kernel<0,0><<<dim3(8, 128), dim3(256), 0, stream>>>(xs, wqs, ipb, qbuf, 1024, 0);
    // attention; writes split O into xs
    attn2_kernel<<<dim3(1024), dim3(256), 0, stream>>>(kbuf, vtbuf, qbuf, xs);
    // gw2 split (aliases kbuf region; kbuf dead after attn2)
    split2_kernel<<<dim3(16), dim3(256), 0, stream>>>(gw2, gw2s, 16384L, 8);
    // attn_out = O @ opw^T + opb -> split fp16 directly (into region2)
    hgemm_kernel<0,1><<<dim3(8, 128), dim3(256), 0, stream>>>(xs, opws, opb, (void*)aos, 2048, 1024);
    // h1 = gelu(attn_out @ gw1^T + gb1) -> split fp16 (into region1)
    hgemm_kernel<1,1><<<dim3(2, 128), dim3(256), 0, stream>>>(aos, gw1s, gb1, (void*)h1s, 512, 256);
    // gate2 + softmax + top2
    gate2_kernel<<<dim3(256), dim3(256), 0, stream>>>(h1s, gw2s, gb2, out);
}

// Round 5
// 630.461 us; speedup vs baseline: 3.1906x; 3.1906x over previous
//
#include <hip/hip_runtime.h>
#include <math.h>

// B=8, S=2048, N=16384 tokens, D=1024, H=16, HD=64, E=64, K(topk)=2
// fp32-accurate fp16-split GEMM: a = a1 + a2/4096 (a1=fp16(a), a2'=fp16((a-a1)*4096))
// C = a1b1 + (a1*b2' + a2'*b1)/4096  (drops a2b2 ~ 2^-22 relative)

typedef _Float16 h8 __attribute__((ext_vector_type(8)));
typedef _Float16 h4 __attribute__((ext_vector_type(4)));
typedef float f4 __attribute__((ext_vector_type(4)));

// LDS tile [128 rows][32 halves]; 16B slots swizzled: slot ^= row&3.
// Spreads the 64B-row-stride ds_read_b128 pattern over 8 banks (2-way, free).
#define SWZ(row, slot) ((row) * 32 + ((((slot) ^ ((row) & 3))) * 8))

__device__ __forceinline__ float gelu_exact(float x) {
    return 0.5f * x * (1.0f + erff(x * 0.70710678118654752f));
}

// ---------------------------------------------------------------------------
// split2: fp32 (rows x cols) -> fp16 (rows x 2*cols): [v1 | (v-v1)*4096]
// cols = 1<<colsh
// ---------------------------------------------------------------------------
__global__ __launch_bounds__(256) void split2_kernel(
    const float* __restrict__ src, _Float16* __restrict__ dst, long total, int colsh) {
    long i = ((long)blockIdx.x * 256 + threadIdx.x) * 4;
    if (i >= total) return;
    f4 v = *(const f4*)(src + i);
    long row = i >> colsh; int col = (int)(i & ((1 << colsh) - 1));
    _Float16* d0 = dst + (row << (colsh + 1)) + col;
    h4 lo, hi;
    #pragma unroll
    for (int j = 0; j < 4; j++) {
        _Float16 a = (_Float16)v[j];
        lo[j] = a;
        hi[j] = (_Float16)((v[j] - (float)a) * 4096.0f);
    }
    *(h4*)d0 = lo;
    *(h4*)(d0 + (1 << colsh)) = hi;
}

// ---------------------------------------------------------------------------
// K1: k/v projections of expert embeddings (fp32, tiny).
// K layout [h][e][hd]; V stored TRANSPOSED [h][hd][e].
// ---------------------------------------------------------------------------
__global__ __launch_bounds__(256) void kv_kernel(
    const float* __restrict__ w, const float* __restrict__ b,
    const float* __restrict__ ee, float* __restrict__ kbuf, float* __restrict__ vtbuf) {
    __shared__ float As[32][68];
    __shared__ float Bs[32][68];
    int tid = threadIdx.x;
    int r0 = blockIdx.x * 64;
    int tx = tid & 15, ty = tid >> 4;
    float acc[4][4] = {};
    const float* wbase = w + (size_t)(1024 + r0) * 1024;
    for (int k0 = 0; k0 < 1024; k0 += 32) {
        #pragma unroll
        for (int i = 0; i < 2; i++) {
            int f = tid + i * 256;
            int row = f >> 3, c4 = f & 7;
            float4 v = *(const float4*)(wbase + (size_t)row * 1024 + k0 + c4 * 4);
            As[c4*4+0][row] = v.x; As[c4*4+1][row] = v.y;
            As[c4*4+2][row] = v.z; As[c4*4+3][row] = v.w;
            float4 u = *(const float4*)(ee + (size_t)row * 1024 + k0 + c4 * 4);
            Bs[c4*4+0][row] = u.x; Bs[c4*4+1][row] = u.y;
            Bs[c4*4+2][row] = u.z; Bs[c4*4+3][row] = u.w;
        }
        __syncthreads();
        #pragma unroll
        for (int kk = 0; kk < 32; kk++) {
            float a[4], bb[4];
            *(float4*)&a[0]  = *(const float4*)&As[kk][ty * 4];
            *(float4*)&bb[0] = *(const float4*)&Bs[kk][tx * 4];
            #pragma unroll
            for (int i = 0; i < 4; i++)
                #pragma unroll
                for (int j = 0; j < 4; j++)
                    acc[i][j] = fmaf(a[i], bb[j], acc[i][j]);
        }
        __syncthreads();
    }
    #pragma unroll
    for (int i = 0; i < 4; i++) {
        int row = r0 + ty * 4 + i;
        float bias = b[1024 + row];
        int j = row & 1023;
        int h = j >> 6, hd = j & 63;
        #pragma unroll
        for (int jj = 0; jj < 4; jj++) {
            int e = tx * 4 + jj;
            float val = acc[i][jj] + bias;
            if (row < 1024) kbuf[h * 4096 + e * 64 + hd] = val;
            else            vtbuf[h * 4096 + hd * 64 + e] = val;
        }
    }
}

// ---------------------------------------------------------------------------
// hgemm: C[M x N] = A_split(M x 2048) x B_split(N x 2048)^T + bias (+GELU)
// fp16 MFMA 16x16x32, 128x128 tile, 256 thr (2x2 waves of 64x64), BK=32.
// Reg-staged global loads (coalesced); XOR-swizzled LDS (write+read).
// OSPLIT: write fp16 split pair (lo at n, hi at nhalf+n) instead of fp32.
// ---------------------------------------------------------------------------
template<int GELU, int OSPLIT>
__global__ __launch_bounds__(256, 2) void hgemm_kernel(
    const _Float16* __restrict__ A, const _Float16* __restrict__ B,
    const float* __restrict__ bias, void* __restrict__ Cv, int ldc, int nhalf) {
    __shared__ __align__(16) _Float16 As[128 * 32];
    __shared__ __align__(16) _Float16 Bl[128 * 32];
    __shared__ __align__(16) _Float16 Bh[128 * 32];
    int tid = threadIdx.x;
    int m0 = blockIdx.y * 128, n0 = blockIdx.x * 128;
    int w = tid >> 6, l = tid & 63;
    int wm = w & 1, wn = w >> 1;
    int lr = l & 15, lk = l >> 4;

    f4 acc1[4][4], acc2[4][4];
    #pragma unroll
    for (int i = 0; i < 4; i++)
        #pragma unroll
        for (int j = 0; j < 4; j++) {
            acc1[i][j] = (f4){0.f, 0.f, 0.f, 0.f};
            acc2[i][j] = (f4){0.f, 0.f, 0.f, 0.f};
        }

    int f0 = tid, f1 = tid + 256;
    int r0 = f0 >> 2, c0 = f0 & 3, r1 = f1 >> 2, c1 = f1 & 3;
    int s0 = SWZ(r0, c0), s1 = SWZ(r1, c1);
    const _Float16* Ab = A + (size_t)m0 * 2048;
    const _Float16* Bb = B + (size_t)n0 * 2048;

    uint4 ua0, ua1, ub0, ub1, uc0, uc1;
    ua0 = *(const uint4*)(Ab + (size_t)r0 * 2048 + c0 * 8);
    ua1 = *(const uint4*)(Ab + (size_t)r1 * 2048 + c1 * 8);
    ub0 = *(const uint4*)(Bb + (size_t)r0 * 2048 + c0 * 8);
    ub1 = *(const uint4*)(Bb + (size_t)r1 * 2048 + c1 * 8);
    uc0 = *(const uint4*)(Bb + (size_t)r0 * 2048 + 1024 + c0 * 8);
    uc1 = *(const uint4*)(Bb + (size_t)r1 * 2048 + 1024 + c1 * 8);

    // ---- phase 1: k in [0,1024): acc1 += a1*b1; acc2 += a1*b2' ----
    for (int kt = 0; kt < 32; kt++) {
        __syncthreads();
        *(uint4*)(As + s0) = ua0; *(uint4*)(As + s1) = ua1;
        *(uint4*)(Bl + s0) = ub0; *(uint4*)(Bl + s1) = ub1;
        *(uint4*)(Bh + s0) = uc0; *(uint4*)(Bh + s1) = uc1;
        __syncthreads();
        if (kt < 31) {
            int ka = (kt + 1) * 32;
            ua0 = *(const uint4*)(Ab + (size_t)r0 * 2048 + ka + c0 * 8);
            ua1 = *(const uint4*)(Ab + (size_t)r1 * 2048 + ka + c1 * 8);
            ub0 = *(const uint4*)(Bb + (size_t)r0 * 2048 + ka + c0 * 8);
            ub1 = *(const uint4*)(Bb + (size_t)r1 * 2048 + ka + c1 * 8);
            uc0 = *(const uint4*)(Bb + (size_t)r0 * 2048 + 1024 + ka + c0 * 8);
            uc1 = *(const uint4*)(Bb + (size_t)r1 * 2048 + 1024 + ka + c1 * 8);
        } else {
            ua0 = *(const uint4*)(Ab + (size_t)r0 * 2048 + 1024 + c0 * 8);
            ua1 = *(const uint4*)(Ab + (size_t)r1 * 2048 + 1024 + c1 * 8);
            uc0 = *(const uint4*)(Bb + (size_t)r0 * 2048 + c0 * 8);
            uc1 = *(const uint4*)(Bb + (size_t)r1 * 2048 + c1 * 8);
        }
        h8 af[4], blf[4], bhf[4];
        #pragma unroll
        for (int mi = 0; mi < 4; mi++)
            af[mi] = *(const h8*)(As + SWZ(wm * 64 + mi * 16 + lr, lk));
        #pragma unroll
        for (int ni = 0; ni < 4; ni++) {
            blf[ni] = *(const h8*)(Bl + SWZ(wn * 64 + ni * 16 + lr, lk));
            bhf[ni] = *(const h8*)(Bh + SWZ(wn * 64 + ni * 16 + lr, lk));
        }
        #pragma unroll
        for (int mi = 0; mi < 4; mi++)
            #pragma unroll
            for (int ni = 0; ni < 4; ni++) {
                acc1[mi][ni] = __builtin_amdgcn_mfma_f32_16x16x32_f16(af[mi], blf[ni], acc1[mi][ni], 0, 0, 0);
                acc2[mi][ni] = __builtin_amdgcn_mfma_f32_16x16x32_f16(af[mi], bhf[ni], acc2[mi][ni], 0, 0, 0);
            }
    }

    // ---- phase 2: k in [1024,2048): acc2 += a2'*b1 ----
    for (int kt = 0; kt < 32; kt++) {
        __syncthreads();
        *(uint4*)(As + s0) = ua0; *(uint4*)(As + s1) = ua1;
        *(uint4*)(Bh + s0) = uc0; *(uint4*)(Bh + s1) = uc1;
        __syncthreads();
        if (kt < 31) {
            int ka = (kt + 1) * 32;
            ua0 = *(const uint4*)(Ab + (size_t)r0 * 2048 + 1024 + ka + c0 * 8);
            ua1 = *(const uint4*)(Ab + (size_t)r1 * 2048 + 1024 + ka + c1 * 8);
            uc0 = *(const uint4*)(Bb + (size_t)r0 * 2048 + ka + c0 * 8);
            uc1 = *(const uint4*)(Bb + (size_t)r1 * 2048 + ka + c1 * 8);
        }
        h8 af[4], bhf[4];
        #pragma unroll
        for (int mi = 0; mi < 4; mi++)
            af[mi] = *(const h8*)(As + SWZ(wm * 64 + mi * 16 + lr, lk));
        #pragma unroll
        for (int ni = 0; ni < 4; ni++)
            bhf[ni] = *(const h8*)(Bh + SWZ(wn * 64 + ni * 16 + lr, lk));
        #pragma unroll
        for (int mi = 0; mi < 4; mi++)
            #pragma unroll
            for (int ni = 0; ni < 4; ni++)
                acc2[mi][ni] = __builtin_amdgcn_mfma_f32_16x16x32_f16(af[mi], bhf[ni], acc2[mi][ni], 0, 0, 0);
    }

    // ---- epilogue: C/D layout col=lane&15, row=(lane>>4)*4+reg ----
    #pragma unroll
    for (int mi = 0; mi < 4; mi++)
        #pragma unroll
        for (int ni = 0; ni < 4; ni++) {
            int n = n0 + wn * 64 + ni * 16 + lr;
            float bn = bias[n];
            #pragma unroll
            for (int j = 0; j < 4; j++) {
                int m = m0 + wm * 64 + mi * 16 + lk * 4 + j;
                float val = acc1[mi][ni][j] + acc2[mi][ni][j] * (1.0f / 4096.0f) + bn;
                if (GELU) val = gelu_exact(val);
                if (OSPLIT) {
                    _Float16* Ch = (_Float16*)Cv;
                    _Float16 lo = (_Float16)val;
                    Ch[(size_t)m * ldc + n] = lo;
                    Ch[(size_t)m * ldc + nhalf + n] = (_Float16)((val - (float)lo) * 4096.0f);
                } else {
                    ((float*)Cv)[(size_t)m * ldc + n] = val;
                }
            }
        }
}

// ---------------------------------------------------------------------------
// attn2: wave-autonomous cross-attention. Each wave: one (b,h,64-token tile).
// lane = expert (scores) AND lane = hd (PV). K rows / V^T rows in registers.
// Writes O directly as fp16 split into os (M x 2048).
// ---------------------------------------------------------------------------
__global__ __launch_bounds__(256) void attn2_kernel(
    const float* __restrict__ kbuf, const float* __restrict__ vtbuf,
    const float* __restrict__ q, _Float16* __restrict__ os) {
    __shared__ __align__(16) float qs[4][64][68];
    __shared__ __align__(16) float ps[4][2][64];
    int tid = threadIdx.x;
    int w = tid >> 6, l = tid & 63;
    int wid = blockIdx.x * 4 + w;
    int b = wid >> 9, h = (wid >> 5) & 15, t0 = (wid & 31) * 64;

    f4 kr[16], vt[16];
    const f4* kp = (const f4*)(kbuf + h * 4096 + l * 64);
    const f4* vp = (const f4*)(vtbuf + h * 4096 + l * 64);
    #pragma unroll
    for (int i = 0; i < 16; i++) { kr[i] = kp[i]; vt[i] = vp[i]; }

    const float* qbase = q + ((size_t)(b * 2048 + t0)) * 1024 + h * 64;
    #pragma unroll
    for (int it = 0; it < 16; it++) {
        int f = it * 64 + l;
        int r = f >> 4, c = f & 15;
        f4 v = *(const f4*)(qbase + (size_t)r * 1024 + c * 4);
        *(f4*)&qs[w][r][c * 4] = v;
    }

    for (int t = 0; t < 64; t++) {
        float s = 0.f;
        #pragma unroll
        for (int i = 0; i < 16; i++) {
            f4 qv = *(const f4*)&qs[w][t][i * 4];
            s = fmaf(qv[0], kr[i][0], s);
            s = fmaf(qv[1], kr[i][1], s);
            s = fmaf(qv[2], kr[i][2], s);
            s = fmaf(qv[3], kr[i][3], s);
        }
        s *= 0.125f;
        float ex = __expf(s);
        float sum = ex;
        #pragma unroll
        for (int off = 32; off; off >>= 1) sum += __shfl_xor(sum, off, 64);
        float p = ex / sum;
        ps[w][t & 1][l] = p;
        float o = 0.f;
        #pragma unroll
        for (int i = 0; i < 16; i++) {
            f4 pv = *(const f4*)&ps[w][t & 1][i * 4];
            o = fmaf(pv[0], vt[i][0], o);
            o = fmaf(pv[1], vt[i][1], o);
            o = fmaf(pv[2], vt[i][2], o);
            o = fmaf(pv[3], vt[i][3], o);
        }
        _Float16 o1 = (_Float16)o;
        _Float16 o2 = (_Float16)((o - (float)o1) * 4096.0f);
        size_t tok = (size_t)(b * 2048 + t0 + t);
        os[tok * 2048 + h * 64 + l] = o1;
        os[tok * 2048 + 1024 + h * 64 + l] = o2;
    }
}

// ---------------------------------------------------------------------------
// gate2: logits(16384x64) = h1s(16384x[256|256]) @ gw2s(64x[256|256])^T + b2
// via 4-product split MFMA (frags straight from global/L2), then fused
// softmax + top-2 + weight normalization. Wave handles 16 tokens.
// ---------------------------------------------------------------------------
__global__ __launch_bounds__(256) void gate2_kernel(
    const _Float16* __restrict__ h1s, const _Float16* __restrict__ w2s,
    const float* __restrict__ b2, float* __restrict__ out) {
    int tid = threadIdx.x;
    int w = tid >> 6, l = tid & 63;
    int lr = l & 15, lk = l >> 4;
    int trow = blockIdx.x * 64 + w * 16;        // wave's 16 tokens

    f4 acc1[4], acc2[4], acc3[4];
    #pragma unroll
    for (int ni = 0; ni < 4; ni++) {
        acc1[ni] = (f4){0.f,0.f,0.f,0.f};
        acc2[ni] = (f4){0.f,0.f,0.f,0.f};
        acc3[ni] = (f4){0.f,0.f,0.f,0.f};
    }
    const _Float16* Arow = h1s + (size_t)(trow + lr) * 512;
    #pragma unroll
    for (int kt = 0; kt < 8; kt++) {
        h8 a1 = *(const h8*)(Arow + kt * 32 + lk * 8);
        h8 a2 = *(const h8*)(Arow + 256 + kt * 32 + lk * 8);
        #pragma unroll
        for (int ni = 0; ni < 4; ni++) {
            const _Float16* Brow = w2s + (size_t)(ni * 16 + lr) * 512;
            h8 b1 = *(const h8*)(Brow + kt * 32 + lk * 8);
            h8 bh = *(const h8*)(Brow + 256 + kt * 32 + lk * 8);
            acc1[ni] = __builtin_amdgcn_mfma_f32_16x16x32_f16(a1, b1, acc1[ni], 0, 0, 0);
            acc2[ni] = __builtin_amdgcn_mfma_f32_16x16x32_f16(a1, bh, acc2[ni], 0, 0, 0);
            acc2[ni] = __builtin_amdgcn_mfma_f32_16x16x32_f16(a2, b1, acc2[ni], 0, 0, 0);
            acc3[ni] = __builtin_amdgcn_mfma_f32_16x16x32_f16(a2, bh, acc3[ni], 0, 0, 0);
        }
    }
    float bcol[4];
    #pragma unroll
    for (int ni = 0; ni < 4; ni++) bcol[ni] = b2[ni * 16 + lr];

    const float c1 = 1.0f / 4096.0f, c2 = 1.0f / 16777216.0f;
    #pragma unroll
    for (int j = 0; j < 4; j++) {
        int tok = trow + lk * 4 + j;
        float lg[4];
        #pragma unroll
        for (int ni = 0; ni < 4; ni++)
            lg[ni] = acc1[ni][j] + acc2[ni][j] * c1 + acc3[ni][j] * c2 + bcol[ni];
        float mx = fmaxf(fmaxf(lg[0], lg[1]), fmaxf(lg[2], lg[3]));
        #pragma unroll
        for (int off = 1; off <= 8; off <<= 1) mx = fmaxf(mx, __shfl_xor(mx, off, 64));
        float pr[4], s = 0.f;
        #pragma unroll
        for (int ni = 0; ni < 4; ni++) { pr[ni] = expf(lg[ni] - mx); s += pr[ni]; }
        #pragma unroll
        for (int off = 1; off <= 8; off <<= 1) s += __shfl_xor(s, off, 64);
        float inv = 1.0f / s;
        float v1 = -1.f, v2 = -1.f; int i1 = 0, i2 = 0;
        #pragma unroll
        for (int ni = 0; ni < 4; ni++) {
            float p = pr[ni] * inv;
            int e = ni * 16 + lr;
            if (p > v1) { v2 = v1; i2 = i1; v1 = p; i1 = e; }
            else if (p > v2) { v2 = p; i2 = e; }
        }
        #pragma unroll
        for (int off = 1; off <= 8; off <<= 1) {
            float u1 = __shfl_xor(v1, off, 64); int k1 = __shfl_xor(i1, off, 64);
            float u2 = __shfl_xor(v2, off, 64); int k2 = __shfl_xor(i2, off, 64);
            if (u1 > v1) {
                if (v1 > u2) { v2 = v1; i2 = i1; } else { v2 = u2; i2 = k2; }
                v1 = u1; i1 = k1;
            } else if (u1 > v2) { v2 = u1; i2 = k1; }
        }
        if (lr == 0) {
            float wsum = v1 + v2 + 1e-8f;
            out[(size_t)tok * 2]     = (float)i1;
            out[(size_t)tok * 2 + 1] = (float)i2;
            out[32768 + (size_t)tok * 2]     = v1 / wsum;
            out[32768 + (size_t)tok * 2 + 1] = v2 / wsum;
        }
    }
}

// ---------------------------------------------------------------------------
extern "C" void kernel_launch(void* const* d_in, const int* in_sizes, int n_in,
                              void* d_out, int out_size, void* d_ws, size_t ws_size,
                              hipStream_t stream) {
    const float* x   = (const float*)d_in[0];
    const float* ee  = (const float*)d_in[1];
    const float* ipw = (const float*)d_in[2];
    const float* ipb = (const float*)d_in[3];
    const float* opw = (const float*)d_in[4];
    const float* opb = (const float*)d_in[5];
    const float* gw1 = (const float*)d_in[6];
    const float* gb1 = (const float*)d_in[7];
    const float* gw2 = (const float*)d_in[8];
    const float* gb2 = (const float*)d_in[9];
    float* out = (float*)d_out;
    char* ws = (char*)d_ws;

    // region1 (64MB): xs (x-split) -> os (O-split) -> h1s (h1-split, 16MB)
    _Float16* xs    = (_Float16*)ws;                          // 16384 x 2048 fp16
    _Float16* h1s   = (_Float16*)ws;                          // 16384 x 512 fp16 (alias)
    // region2 (64MB): qbuf (Q fp32) -> aos (attn_out split fp16)
    float*    qbuf  = (float*)(ws + 67108864);                // 16384 x 1024 f32
    _Float16* aos   = (_Float16*)(ws + 67108864);             // 16384 x 2048 fp16 (alias)
    _Float16* wqs   = (_Float16*)(ws + 134217728);            // 1024 x 2048
    _Float16* opws  = (_Float16*)(ws + 138412032);            // 1024 x 2048
    _Float16* gw1s  = (_Float16*)(ws + 142606336);            // 256 x 2048
    float*    kbuf  = (float*)(ws + 143654912);               // 16x64x64 f32
    _Float16* gw2s  = (_Float16*)(ws + 143654912);            // 64 x 512 (aliases kbuf, used after attn)
    float*    vtbuf = (float*)(ws + 143917056);               // 16x64x64 f32 (transposed)

    split2_kernel<<<dim3(1024),  dim3(256), 0, stream>>>(ipw, wqs, 1048576L, 10);
    split2_kernel<<<dim3(1024),  dim3(256), 0, stream>>>(opw, opws, 1048576L, 10);
    split2_kernel<<<dim3(256),   dim3(256), 0, stream>>>(gw1, gw1s, 262144L, 10);
    split2_kernel<<<dim3(16384), dim3(256), 0, stream>>>(x, xs, 16777216L, 10);
    kv_kernel<<<dim3(32), dim3(256), 0, stream>>>(ipw, ipb, ee, kbuf, vtbuf);
    // Q = x @ wq^T + bq (fp32 out)
    hgemm_kernel<0,0><<<dim3(8, 128), dim3(256), 0, stream>>>(xs, wqs, ipb, qbuf, 1024, 0);
    // attention; writes split O into xs
    attn2_kernel<<<dim3(1024), dim3(256), 0, stream>>>(kbuf, vtbuf, qbuf, xs);
    // gw2 split (aliases kbuf region; kbuf dead after attn2)
    split2_kernel<<<dim3(16), dim3(256), 0, stream>>>(gw2, gw2s, 16384L, 8);
    // attn_out = O @ opw^T + opb -> split fp16 directly (into region2)
    hgemm_kernel<0,1><<<dim3(8, 128), dim3(256), 0, stream>>>(xs, opws, opb, (void*)aos, 2048, 1024);
    // h1 = gelu(attn_out @ gw1^T + gb1) -> split fp16 (into region1)
    hgemm_kernel<1,1><<<dim3(2, 128), dim3(256), 0, stream>>>(aos, gw1s, gb1, (void*)h1s, 512, 256);
    // gate2 + softmax + top2
    gate2_kernel<<<dim3(256), dim3(256), 0, stream>>>(h1s, gw2s, gb2, out);
}

// Round 6
// 570.544 us; speedup vs baseline: 3.5257x; 1.1050x over previous
//
#include <hip/hip_runtime.h>
#include <math.h>

// B=8, S=2048, N=16384 tokens, D=1024, H=16, HD=64, E=64, K(topk)=2
// fp32-accurate fp16-split GEMM: a = a1 + a2/4096 (a1=fp16(a), a2'=fp16((a-a1)*4096))
// C = a1b1 + (a1*b2' + a2'*b1)/4096  (drops a2b2 ~ 2^-22 relative)
// Merged single K-loop: per kt stage {a1,a2,b1,bh} and do 48 MFMA (was 2 loops).

typedef _Float16 h8 __attribute__((ext_vector_type(8)));
typedef _Float16 h4 __attribute__((ext_vector_type(4)));
typedef float f4 __attribute__((ext_vector_type(4)));

__device__ __forceinline__ float gelu_exact(float x) {
    return 0.5f * x * (1.0f + erff(x * 0.70710678118654752f));
}

// ---------------------------------------------------------------------------
// split2: fp32 (rows x cols) -> fp16 (rows x 2*cols): [v1 | (v-v1)*4096]
// ---------------------------------------------------------------------------
__global__ __launch_bounds__(256) void split2_kernel(
    const float* __restrict__ src, _Float16* __restrict__ dst, long total, int colsh) {
    long i = ((long)blockIdx.x * 256 + threadIdx.x) * 4;
    if (i >= total) return;
    f4 v = *(const f4*)(src + i);
    long row = i >> colsh; int col = (int)(i & ((1 << colsh) - 1));
    _Float16* d0 = dst + (row << (colsh + 1)) + col;
    h4 lo, hi;
    #pragma unroll
    for (int j = 0; j < 4; j++) {
        _Float16 a = (_Float16)v[j];
        lo[j] = a;
        hi[j] = (_Float16)((v[j] - (float)a) * 4096.0f);
    }
    *(h4*)d0 = lo;
    *(h4*)(d0 + (1 << colsh)) = hi;
}

// ---------------------------------------------------------------------------
// K1: k/v projections of expert embeddings (fp32, tiny).
// K layout [h][e][hd]; V stored TRANSPOSED [h][hd][e].
// ---------------------------------------------------------------------------
__global__ __launch_bounds__(256) void kv_kernel(
    const float* __restrict__ w, const float* __restrict__ b,
    const float* __restrict__ ee, float* __restrict__ kbuf, float* __restrict__ vtbuf) {
    __shared__ float As[32][68];
    __shared__ float Bs[32][68];
    int tid = threadIdx.x;
    int r0 = blockIdx.x * 64;
    int tx = tid & 15, ty = tid >> 4;
    float acc[4][4] = {};
    const float* wbase = w + (size_t)(1024 + r0) * 1024;
    for (int k0 = 0; k0 < 1024; k0 += 32) {
        #pragma unroll
        for (int i = 0; i < 2; i++) {
            int f = tid + i * 256;
            int row = f >> 3, c4 = f & 7;
            float4 v = *(const float4*)(wbase + (size_t)row * 1024 + k0 + c4 * 4);
            As[c4*4+0][row] = v.x; As[c4*4+1][row] = v.y;
            As[c4*4+2][row] = v.z; As[c4*4+3][row] = v.w;
            float4 u = *(const float4*)(ee + (size_t)row * 1024 + k0 + c4 * 4);
            Bs[c4*4+0][row] = u.x; Bs[c4*4+1][row] = u.y;
            Bs[c4*4+2][row] = u.z; Bs[c4*4+3][row] = u.w;
        }
        __syncthreads();
        #pragma unroll
        for (int kk = 0; kk < 32; kk++) {
            float a[4], bb[4];
            *(float4*)&a[0]  = *(const float4*)&As[kk][ty * 4];
            *(float4*)&bb[0] = *(const float4*)&Bs[kk][tx * 4];
            #pragma unroll
            for (int i = 0; i < 4; i++)
                #pragma unroll
                for (int j = 0; j < 4; j++)
                    acc[i][j] = fmaf(a[i], bb[j], acc[i][j]);
        }
        __syncthreads();
    }
    #pragma unroll
    for (int i = 0; i < 4; i++) {
        int row = r0 + ty * 4 + i;
        float bias = b[1024 + row];
        int j = row & 1023;
        int h = j >> 6, hd = j & 63;
        #pragma unroll
        for (int jj = 0; jj < 4; jj++) {
            int e = tx * 4 + jj;
            float val = acc[i][jj] + bias;
            if (row < 1024) kbuf[h * 4096 + e * 64 + hd] = val;
            else            vtbuf[h * 4096 + hd * 64 + e] = val;
        }
    }
}

// ---------------------------------------------------------------------------
// hgemm: C[M x N] = A_split(M x 2048) @ B_split(N x 2048)^T + bias (+GELU)
// fp16 MFMA 16x16x32, 128x128 tile, 256 thr (2x2 waves of 64x64), BK=32.
// Single merged K-loop, 4 LDS streams {a1,a2,b1,bh}, 48 MFMA per kt.
// AF32: A source is raw fp32 (stride 1024); split computed during staging.
// OSPLIT: write fp16 split pair (lo at n, hi at nhalf+n) instead of fp32.
// XCD-chunked block swizzle (bijective; grid counts are multiples of 8).
// ---------------------------------------------------------------------------
template<int GELU, int OSPLIT, int AF32>
__global__ __launch_bounds__(256, 2) void hgemm_kernel(
    const void* __restrict__ Av, const _Float16* __restrict__ B,
    const float* __restrict__ bias, void* __restrict__ Cv, int ldc, int nhalf) {
    __shared__ __align__(16) _Float16 As[128 * 32];
    __shared__ __align__(16) _Float16 Ah[128 * 32];
    __shared__ __align__(16) _Float16 Bl[128 * 32];
    __shared__ __align__(16) _Float16 Bh[128 * 32];
    int tid = threadIdx.x;

    int gx = gridDim.x;
    int nwg = gx * gridDim.y;
    int lid = blockIdx.y * gx + blockIdx.x;
    int L = (lid & 7) * (nwg >> 3) + (lid >> 3);    // XCD-chunked, bijective
    int m0 = (L / gx) * 128, n0 = (L % gx) * 128;

    int w = tid >> 6, l = tid & 63;
    int wm = w & 1, wn = w >> 1;
    int lr = l & 15, lk = l >> 4;

    f4 acc1[4][4], acc2[4][4];
    #pragma unroll
    for (int i = 0; i < 4; i++)
        #pragma unroll
        for (int j = 0; j < 4; j++) {
            acc1[i][j] = (f4){0.f, 0.f, 0.f, 0.f};
            acc2[i][j] = (f4){0.f, 0.f, 0.f, 0.f};
        }

    int r0 = tid >> 2, c0 = tid & 3;                // fp16 staging: 2 rows/thread
    int s0 = r0 * 32 + c0 * 8, s1 = s0 + 64 * 32;
    int rb = tid >> 3, c4 = tid & 7;                // fp32 staging: 4 rows/thread

    const _Float16* Ab = (const _Float16*)Av + (size_t)m0 * 2048;
    const float*    Af = (const float*)Av + (size_t)m0 * 1024;
    const _Float16* Bb = B + (size_t)n0 * 2048;

    float4 xa[4];
    uint4 ua0, ua1, uh0, uh1, ub0, ub1, uc0, uc1;
    if (AF32) {
        #pragma unroll
        for (int f = 0; f < 4; f++)
            xa[f] = *(const float4*)(Af + (size_t)(rb + f * 32) * 1024 + c4 * 4);
    } else {
        ua0 = *(const uint4*)(Ab + (size_t)r0 * 2048 + c0 * 8);
        ua1 = *(const uint4*)(Ab + (size_t)(r0 + 64) * 2048 + c0 * 8);
        uh0 = *(const uint4*)(Ab + (size_t)r0 * 2048 + 1024 + c0 * 8);
        uh1 = *(const uint4*)(Ab + (size_t)(r0 + 64) * 2048 + 1024 + c0 * 8);
    }
    ub0 = *(const uint4*)(Bb + (size_t)r0 * 2048 + c0 * 8);
    ub1 = *(const uint4*)(Bb + (size_t)(r0 + 64) * 2048 + c0 * 8);
    uc0 = *(const uint4*)(Bb + (size_t)r0 * 2048 + 1024 + c0 * 8);
    uc1 = *(const uint4*)(Bb + (size_t)(r0 + 64) * 2048 + 1024 + c0 * 8);

    for (int kt = 0; kt < 32; kt++) {
        __syncthreads();
        if (AF32) {
            #pragma unroll
            for (int f = 0; f < 4; f++) {
                h4 lo, hi;
                #pragma unroll
                for (int j = 0; j < 4; j++) {
                    float v = ((const float*)&xa[f])[j];
                    _Float16 a = (_Float16)v;
                    lo[j] = a;
                    hi[j] = (_Float16)((v - (float)a) * 4096.0f);
                }
                *(h4*)(As + (rb + f * 32) * 32 + c4 * 4) = lo;
                *(h4*)(Ah + (rb + f * 32) * 32 + c4 * 4) = hi;
            }
        } else {
            *(uint4*)(As + s0) = ua0; *(uint4*)(As + s1) = ua1;
            *(uint4*)(Ah + s0) = uh0; *(uint4*)(Ah + s1) = uh1;
        }
        *(uint4*)(Bl + s0) = ub0; *(uint4*)(Bl + s1) = ub1;
        *(uint4*)(Bh + s0) = uc0; *(uint4*)(Bh + s1) = uc1;
        __syncthreads();
        if (kt < 31) {
            int ka = (kt + 1) * 32;
            if (AF32) {
                #pragma unroll
                for (int f = 0; f < 4; f++)
                    xa[f] = *(const float4*)(Af + (size_t)(rb + f * 32) * 1024 + ka + c4 * 4);
            } else {
                ua0 = *(const uint4*)(Ab + (size_t)r0 * 2048 + ka + c0 * 8);
                ua1 = *(const uint4*)(Ab + (size_t)(r0 + 64) * 2048 + ka + c0 * 8);
                uh0 = *(const uint4*)(Ab + (size_t)r0 * 2048 + 1024 + ka + c0 * 8);
                uh1 = *(const uint4*)(Ab + (size_t)(r0 + 64) * 2048 + 1024 + ka + c0 * 8);
            }
            ub0 = *(const uint4*)(Bb + (size_t)r0 * 2048 + ka + c0 * 8);
            ub1 = *(const uint4*)(Bb + (size_t)(r0 + 64) * 2048 + ka + c0 * 8);
            uc0 = *(const uint4*)(Bb + (size_t)r0 * 2048 + 1024 + ka + c0 * 8);
            uc1 = *(const uint4*)(Bb + (size_t)(r0 + 64) * 2048 + 1024 + ka + c0 * 8);
        }
        // fragment reads + 48 MFMA (a1*b1 -> acc1; a1*bh, a2*b1 -> acc2)
        h8 a1f[4], blf[4], bhf[4];
        #pragma unroll
        for (int mi = 0; mi < 4; mi++)
            a1f[mi] = *(const h8*)(As + (wm * 64 + mi * 16 + lr) * 32 + lk * 8);
        #pragma unroll
        for (int ni = 0; ni < 4; ni++) {
            blf[ni] = *(const h8*)(Bl + (wn * 64 + ni * 16 + lr) * 32 + lk * 8);
            bhf[ni] = *(const h8*)(Bh + (wn * 64 + ni * 16 + lr) * 32 + lk * 8);
        }
        #pragma unroll
        for (int mi = 0; mi < 4; mi++)
            #pragma unroll
            for (int ni = 0; ni < 4; ni++) {
                acc1[mi][ni] = __builtin_amdgcn_mfma_f32_16x16x32_f16(a1f[mi], blf[ni], acc1[mi][ni], 0, 0, 0);
                acc2[mi][ni] = __builtin_amdgcn_mfma_f32_16x16x32_f16(a1f[mi], bhf[ni], acc2[mi][ni], 0, 0, 0);
            }
        h8 a2f[4];
        #pragma unroll
        for (int mi = 0; mi < 4; mi++)
            a2f[mi] = *(const h8*)(Ah + (wm * 64 + mi * 16 + lr) * 32 + lk * 8);
        #pragma unroll
        for (int mi = 0; mi < 4; mi++)
            #pragma unroll
            for (int ni = 0; ni < 4; ni++)
                acc2[mi][ni] = __builtin_amdgcn_mfma_f32_16x16x32_f16(a2f[mi], blf[ni], acc2[mi][ni], 0, 0, 0);
    }

    // ---- epilogue: C/D layout col=lane&15, row=(lane>>4)*4+reg ----
    #pragma unroll
    for (int mi = 0; mi < 4; mi++)
        #pragma unroll
        for (int ni = 0; ni < 4; ni++) {
            int n = n0 + wn * 64 + ni * 16 + lr;
            float bn = bias[n];
            #pragma unroll
            for (int j = 0; j < 4; j++) {
                int m = m0 + wm * 64 + mi * 16 + lk * 4 + j;
                float val = acc1[mi][ni][j] + acc2[mi][ni][j] * (1.0f / 4096.0f) + bn;
                if (GELU) val = gelu_exact(val);
                if (OSPLIT) {
                    _Float16* Ch = (_Float16*)Cv;
                    _Float16 lo = (_Float16)val;
                    Ch[(size_t)m * ldc + n] = lo;
                    Ch[(size_t)m * ldc + nhalf + n] = (_Float16)((val - (float)lo) * 4096.0f);
                } else {
                    ((float*)Cv)[(size_t)m * ldc + n] = val;
                }
            }
        }
}

// ---------------------------------------------------------------------------
// attn2: wave-autonomous cross-attention. Each wave: one (b,h,64-token tile).
// lane = expert (scores) AND lane = hd (PV). K rows / V^T rows in registers.
// Writes O directly as fp16 split into os (M x 2048).
// ---------------------------------------------------------------------------
__global__ __launch_bounds__(256) void attn2_kernel(
    const float* __restrict__ kbuf, const float* __restrict__ vtbuf,
    const float* __restrict__ q, _Float16* __restrict__ os) {
    __shared__ __align__(16) float qs[4][64][68];
    __shared__ __align__(16) float ps[4][2][64];
    int tid = threadIdx.x;
    int w = tid >> 6, l = tid & 63;
    int wid = blockIdx.x * 4 + w;
    int b = wid >> 9, h = (wid >> 5) & 15, t0 = (wid & 31) * 64;

    f4 kr[16], vt[16];
    const f4* kp = (const f4*)(kbuf + h * 4096 + l * 64);
    const f4* vp = (const f4*)(vtbuf + h * 4096 + l * 64);
    #pragma unroll
    for (int i = 0; i < 16; i++) { kr[i] = kp[i]; vt[i] = vp[i]; }

    const float* qbase = q + ((size_t)(b * 2048 + t0)) * 1024 + h * 64;
    #pragma unroll
    for (int it = 0; it < 16; it++) {
        int f = it * 64 + l;
        int r = f >> 4, c = f & 15;
        f4 v = *(const f4*)(qbase + (size_t)r * 1024 + c * 4);
        *(f4*)&qs[w][r][c * 4] = v;
    }

    for (int t = 0; t < 64; t++) {
        float s = 0.f;
        #pragma unroll
        for (int i = 0; i < 16; i++) {
            f4 qv = *(const f4*)&qs[w][t][i * 4];
            s = fmaf(qv[0], kr[i][0], s);
            s = fmaf(qv[1], kr[i][1], s);
            s = fmaf(qv[2], kr[i][2], s);
            s = fmaf(qv[3], kr[i][3], s);
        }
        s *= 0.125f;
        float ex = __expf(s);
        float sum = ex;
        #pragma unroll
        for (int off = 32; off; off >>= 1) sum += __shfl_xor(sum, off, 64);
        float p = ex / sum;
        ps[w][t & 1][l] = p;
        float o = 0.f;
        #pragma unroll
        for (int i = 0; i < 16; i++) {
            f4 pv = *(const f4*)&ps[w][t & 1][i * 4];
            o = fmaf(pv[0], vt[i][0], o);
            o = fmaf(pv[1], vt[i][1], o);
            o = fmaf(pv[2], vt[i][2], o);
            o = fmaf(pv[3], vt[i][3], o);
        }
        _Float16 o1 = (_Float16)o;
        _Float16 o2 = (_Float16)((o - (float)o1) * 4096.0f);
        size_t tok = (size_t)(b * 2048 + t0 + t);
        os[tok * 2048 + h * 64 + l] = o1;
        os[tok * 2048 + 1024 + h * 64 + l] = o2;
    }
}

// ---------------------------------------------------------------------------
// gate2: logits(16384x64) = h1s(16384x[256|256]) @ gw2s(64x[256|256])^T + b2
// via 4-product split MFMA (frags straight from global/L2), then fused
// softmax + top-2 + weight normalization. Wave handles 16 tokens.
// ---------------------------------------------------------------------------
__global__ __launch_bounds__(256) void gate2_kernel(
    const _Float16* __restrict__ h1s, const _Float16* __restrict__ w2s,
    const float* __restrict__ b2, float* __restrict__ out) {
    int tid = threadIdx.x;
    int w = tid >> 6, l = tid & 63;
    int lr = l & 15, lk = l >> 4;
    int trow = blockIdx.x * 64 + w * 16;        // wave's 16 tokens

    f4 acc1[4], acc2[4], acc3[4];
    #pragma unroll
    for (int ni = 0; ni < 4; ni++) {
        acc1[ni] = (f4){0.f,0.f,0.f,0.f};
        acc2[ni] = (f4){0.f,0.f,0.f,0.f};
        acc3[ni] = (f4){0.f,0.f,0.f,0.f};
    }
    const _Float16* Arow = h1s + (size_t)(trow + lr) * 512;
    #pragma unroll
    for (int kt = 0; kt < 8; kt++) {
        h8 a1 = *(const h8*)(Arow + kt * 32 + lk * 8);
        h8 a2 = *(const h8*)(Arow + 256 + kt * 32 + lk * 8);
        #pragma unroll
        for (int ni = 0; ni < 4; ni++) {
            const _Float16* Brow = w2s + (size_t)(ni * 16 + lr) * 512;
            h8 b1 = *(const h8*)(Brow + kt * 32 + lk * 8);
            h8 bh = *(const h8*)(Brow + 256 + kt * 32 + lk * 8);
            acc1[ni] = __builtin_amdgcn_mfma_f32_16x16x32_f16(a1, b1, acc1[ni], 0, 0, 0);
            acc2[ni] = __builtin_amdgcn_mfma_f32_16x16x32_f16(a1, bh, acc2[ni], 0, 0, 0);
            acc2[ni] = __builtin_amdgcn_mfma_f32_16x16x32_f16(a2, b1, acc2[ni], 0, 0, 0);
            acc3[ni] = __builtin_amdgcn_mfma_f32_16x16x32_f16(a2, bh, acc3[ni], 0, 0, 0);
        }
    }
    float bcol[4];
    #pragma unroll
    for (int ni = 0; ni < 4; ni++) bcol[ni] = b2[ni * 16 + lr];

    const float c1 = 1.0f / 4096.0f, c2 = 1.0f / 16777216.0f;
    #pragma unroll
    for (int j = 0; j < 4; j++) {
        int tok = trow + lk * 4 + j;
        float lg[4];
        #pragma unroll
        for (int ni = 0; ni < 4; ni++)
            lg[ni] = acc1[ni][j] + acc2[ni][j] * c1 + acc3[ni][j] * c2 + bcol[ni];
        float mx = fmaxf(fmaxf(lg[0], lg[1]), fmaxf(lg[2], lg[3]));
        #pragma unroll
        for (int off = 1; off <= 8; off <<= 1) mx = fmaxf(mx, __shfl_xor(mx, off, 64));
        float pr[4], s = 0.f;
        #pragma unroll
        for (int ni = 0; ni < 4; ni++) { pr[ni] = expf(lg[ni] - mx); s += pr[ni]; }
        #pragma unroll
        for (int off = 1; off <= 8; off <<= 1) s += __shfl_xor(s, off, 64);
        float inv = 1.0f / s;
        float v1 = -1.f, v2 = -1.f; int i1 = 0, i2 = 0;
        #pragma unroll
        for (int ni = 0; ni < 4; ni++) {
            float p = pr[ni] * inv;
            int e = ni * 16 + lr;
            if (p > v1) { v2 = v1; i2 = i1; v1 = p; i1 = e; }
            else if (p > v2) { v2 = p; i2 = e; }
        }
        #pragma unroll
        for (int off = 1; off <= 8; off <<= 1) {
            float u1 = __shfl_xor(v1, off, 64); int k1 = __shfl_xor(i1, off, 64);
            float u2 = __shfl_xor(v2, off, 64); int k2 = __shfl_xor(i2, off, 64);
            if (u1 > v1) {
                if (v1 > u2) { v2 = v1; i2 = i1; } else { v2 = u2; i2 = k2; }
                v1 = u1; i1 = k1;
            } else if (u1 > v2) { v2 = u1; i2 = k1; }
        }
        if (lr == 0) {
            float wsum = v1 + v2 + 1e-8f;
            out[(size_t)tok * 2]     = (float)i1;
            out[(size_t)tok * 2 + 1] = (float)i2;
            out[32768 + (size_t)tok * 2]     = v1 / wsum;
            out[32768 + (size_t)tok * 2 + 1] = v2 / wsum;
        }
    }
}

// ---------------------------------------------------------------------------
extern "C" void kernel_launch(void* const* d_in, const int* in_sizes, int n_in,
                              void* d_out, int out_size, void* d_ws, size_t ws_size,
                              hipStream_t stream) {
    const float* x   = (const float*)d_in[0];
    const float* ee  = (const float*)d_in[1];
    const float* ipw = (const float*)d_in[2];
    const float* ipb = (const float*)d_in[3];
    const float* opw = (const float*)d_in[4];
    const float* opb = (const float*)d_in[5];
    const float* gw1 = (const float*)d_in[6];
    const float* gb1 = (const float*)d_in[7];
    const float* gw2 = (const float*)d_in[8];
    const float* gb2 = (const float*)d_in[9];
    float* out = (float*)d_out;
    char* ws = (char*)d_ws;

    // region1 (64MB): os (O-split from attn) -> h1s (h1-split, 16MB)
    _Float16* os    = (_Float16*)ws;                          // 16384 x 2048 fp16
    _Float16* h1s   = (_Float16*)ws;                          // 16384 x 512 fp16 (alias)
    // region2 (64MB): qbuf (Q fp32) -> aos (attn_out split fp16)
    float*    qbuf  = (float*)(ws + 67108864);                // 16384 x 1024 f32
    _Float16* aos   = (_Float16*)(ws + 67108864);             // 16384 x 2048 fp16 (alias)
    _Float16* wqs   = (_Float16*)(ws + 134217728);            // 1024 x 2048
    _Float16* opws  = (_Float16*)(ws + 138412032);            // 1024 x 2048
    _Float16* gw1s  = (_Float16*)(ws + 142606336);            // 256 x 2048
    float*    kbuf  = (float*)(ws + 143654912);               // 16x64x64 f32
    _Float16* gw2s  = (_Float16*)(ws + 143654912);            // 64 x 512 (aliases kbuf, used after attn)
    float*    vtbuf = (float*)(ws + 143917056);               // 16x64x64 f32 (transposed)

    split2_kernel<<<dim3(1024), dim3(256), 0, stream>>>(ipw, wqs, 1048576L, 10);
    split2_kernel<<<dim3(1024), dim3(256), 0, stream>>>(opw, opws, 1048576L, 10);
    split2_kernel<<<dim3(256),  dim3(256), 0, stream>>>(gw1, gw1s, 262144L, 10);
    kv_kernel<<<dim3(32), dim3(256), 0, stream>>>(ipw, ipb, ee, kbuf, vtbuf);
    // Q = x @ wq^T + bq (fp32 A staged+split in-kernel, fp32 out)
    hgemm_kernel<0,0,1><<<dim3(8, 128), dim3(256), 0, stream>>>(x, wqs, ipb, qbuf, 1024, 0);
    // attention; writes split O into region1
    attn2_kernel<<<dim3(1024), dim3(256), 0, stream>>>(kbuf, vtbuf, qbuf, os);
    // gw2 split (aliases kbuf region; kbuf dead after attn2)
    split2_kernel<<<dim3(16), dim3(256), 0, stream>>>(gw2, gw2s, 16384L, 8);
    // attn_out = O @ opw^T + opb -> split fp16 directly (into region2)
    hgemm_kernel<0,1,0><<<dim3(8, 128), dim3(256), 0, stream>>>(os, opws, opb, (void*)aos, 2048, 1024);
    // h1 = gelu(attn_out @ gw1^T + gb1) -> split fp16 (into region1)
    hgemm_kernel<1,1,0><<<dim3(2, 128), dim3(256), 0, stream>>>(aos, gw1s, gb1, (void*)h1s, 512, 256);
    // gate2 + softmax + top2
    gate2_kernel<<<dim3(256), dim3(256), 0, stream>>>(h1s, gw2s, gb2, out);
}

// Round 7
// 550.811 us; speedup vs baseline: 3.6520x; 1.0358x over previous
//
#include <hip/hip_runtime.h>
#include <math.h>

// B=8, S=2048, N=16384 tokens, D=1024, H=16, HD=64, E=64, K(topk)=2
// fp32-accurate fp16-split GEMM: a = a1 + a2/4096 (a1=fp16(a), a2'=fp16((a-a1)*4096))
// C = a1b1 + (a1*b2' + a2'*b1)/4096  (drops a2b2 ~ 2^-22 relative)
// Pipeline: LDS double-buffer, 1 raw barrier + lgkmcnt(0) per K-step, global
// loads for tile t+2 in flight across the barrier (no vmcnt(0) drain).

typedef _Float16 h8 __attribute__((ext_vector_type(8)));
typedef _Float16 h4 __attribute__((ext_vector_type(4)));
typedef float f4 __attribute__((ext_vector_type(4)));

#define BAR() do { \
    asm volatile("s_waitcnt lgkmcnt(0)" ::: "memory"); \
    __builtin_amdgcn_s_barrier(); \
    __builtin_amdgcn_sched_barrier(0); } while (0)

__device__ __forceinline__ float gelu_exact(float x) {
    return 0.5f * x * (1.0f + erff(x * 0.70710678118654752f));
}

// ---------------------------------------------------------------------------
// split2: fp32 (rows x cols) -> fp16 (rows x 2*cols): [v1 | (v-v1)*4096]
// ---------------------------------------------------------------------------
__global__ __launch_bounds__(256) void split2_kernel(
    const float* __restrict__ src, _Float16* __restrict__ dst, long total, int colsh) {
    long i = ((long)blockIdx.x * 256 + threadIdx.x) * 4;
    if (i >= total) return;
    f4 v = *(const f4*)(src + i);
    long row = i >> colsh; int col = (int)(i & ((1 << colsh) - 1));
    _Float16* d0 = dst + (row << (colsh + 1)) + col;
    h4 lo, hi;
    #pragma unroll
    for (int j = 0; j < 4; j++) {
        _Float16 a = (_Float16)v[j];
        lo[j] = a;
        hi[j] = (_Float16)((v[j] - (float)a) * 4096.0f);
    }
    *(h4*)d0 = lo;
    *(h4*)(d0 + (1 << colsh)) = hi;
}

// ---------------------------------------------------------------------------
// K1: k/v projections of expert embeddings (fp32, tiny).
// K layout [h][e][hd]; V stored TRANSPOSED [h][hd][e].
// ---------------------------------------------------------------------------
__global__ __launch_bounds__(256) void kv_kernel(
    const float* __restrict__ w, const float* __restrict__ b,
    const float* __restrict__ ee, float* __restrict__ kbuf, float* __restrict__ vtbuf) {
    __shared__ float As[32][68];
    __shared__ float Bs[32][68];
    int tid = threadIdx.x;
    int r0 = blockIdx.x * 64;
    int tx = tid & 15, ty = tid >> 4;
    float acc[4][4] = {};
    const float* wbase = w + (size_t)(1024 + r0) * 1024;
    for (int k0 = 0; k0 < 1024; k0 += 32) {
        #pragma unroll
        for (int i = 0; i < 2; i++) {
            int f = tid + i * 256;
            int row = f >> 3, c4 = f & 7;
            float4 v = *(const float4*)(wbase + (size_t)row * 1024 + k0 + c4 * 4);
            As[c4*4+0][row] = v.x; As[c4*4+1][row] = v.y;
            As[c4*4+2][row] = v.z; As[c4*4+3][row] = v.w;
            float4 u = *(const float4*)(ee + (size_t)row * 1024 + k0 + c4 * 4);
            Bs[c4*4+0][row] = u.x; Bs[c4*4+1][row] = u.y;
            Bs[c4*4+2][row] = u.z; Bs[c4*4+3][row] = u.w;
        }
        __syncthreads();
        #pragma unroll
        for (int kk = 0; kk < 32; kk++) {
            float a[4], bb[4];
            *(float4*)&a[0]  = *(const float4*)&As[kk][ty * 4];
            *(float4*)&bb[0] = *(const float4*)&Bs[kk][tx * 4];
            #pragma unroll
            for (int i = 0; i < 4; i++)
                #pragma unroll
                for (int j = 0; j < 4; j++)
                    acc[i][j] = fmaf(a[i], bb[j], acc[i][j]);
        }
        __syncthreads();
    }
    #pragma unroll
    for (int i = 0; i < 4; i++) {
        int row = r0 + ty * 4 + i;
        float bias = b[1024 + row];
        int j = row & 1023;
        int h = j >> 6, hd = j & 63;
        #pragma unroll
        for (int jj = 0; jj < 4; jj++) {
            int e = tx * 4 + jj;
            float val = acc[i][jj] + bias;
            if (row < 1024) kbuf[h * 4096 + e * 64 + hd] = val;
            else            vtbuf[h * 4096 + hd * 64 + e] = val;
        }
    }
}

// ---------------------------------------------------------------------------
// hgemm: C[M x N] = A_split(M x 2048) @ B_split(N x 2048)^T + bias (+GELU)
// fp16 MFMA 16x16x32, 128x128 tile, 256 thr (2x2 waves of 64x64), BK=32.
// Double-buffered LDS (2 x 4 streams x 8KB = 64KB), 1 barrier/K-step,
// 48 MFMA per K-step, loads for t+2 outstanding across the barrier.
// AF32: A source is raw fp32 (stride 1024); split computed during staging.
// OSPLIT: write fp16 split pair (lo at n, hi at nhalf+n) instead of fp32.
// XCD-chunked block swizzle (bijective; grid counts are multiples of 8).
// ---------------------------------------------------------------------------
template<int GELU, int OSPLIT, int AF32>
__global__ __launch_bounds__(256, 2) void hgemm_kernel(
    const void* __restrict__ Av, const _Float16* __restrict__ B,
    const float* __restrict__ bias, void* __restrict__ Cv, int ldc, int nhalf) {
    // lds[buf][stream][128*32]: streams 0=a1, 1=a2, 2=b1, 3=bh
    __shared__ __align__(16) _Float16 lds[2][4][128 * 32];
    const int NT = 32;
    int tid = threadIdx.x;

    int gx = gridDim.x;
    int nwg = gx * gridDim.y;
    int lid = blockIdx.y * gx + blockIdx.x;
    int L = (lid & 7) * (nwg >> 3) + (lid >> 3);    // XCD-chunked, bijective
    int m0 = (L / gx) * 128, n0 = (L % gx) * 128;

    int w = tid >> 6, l = tid & 63;
    int wm = w & 1, wn = w >> 1;
    int lr = l & 15, lk = l >> 4;

    f4 acc1[4][4], acc2[4][4];
    #pragma unroll
    for (int i = 0; i < 4; i++)
        #pragma unroll
        for (int j = 0; j < 4; j++) {
            acc1[i][j] = (f4){0.f, 0.f, 0.f, 0.f};
            acc2[i][j] = (f4){0.f, 0.f, 0.f, 0.f};
        }

    int r0 = tid >> 2, c0 = tid & 3;                // fp16 staging: 2 rows/thread
    int s0 = r0 * 32 + c0 * 8, s1 = s0 + 64 * 32;
    int rb = tid >> 3, c4 = tid & 7;                // fp32 staging: 4 rows/thread

    const _Float16* Ab = (const _Float16*)Av + (size_t)m0 * 2048;
    const float*    Af = (const float*)Av + (size_t)m0 * 1024;
    const _Float16* Bb = B + (size_t)n0 * 2048;

    float4 xa[4];
    uint4 ua0, ua1, uh0, uh1, ub0, ub1, uc0, uc1;

#define LOADT(kt) do { int ka_ = (kt) * 32;                                         \
    if (AF32) {                                                                     \
        _Pragma("unroll")                                                           \
        for (int f = 0; f < 4; f++)                                                 \
            xa[f] = *(const float4*)(Af + (size_t)(rb + f * 32) * 1024 + ka_ + c4 * 4); \
    } else {                                                                        \
        ua0 = *(const uint4*)(Ab + (size_t)r0 * 2048 + ka_ + c0 * 8);               \
        ua1 = *(const uint4*)(Ab + (size_t)(r0 + 64) * 2048 + ka_ + c0 * 8);        \
        uh0 = *(const uint4*)(Ab + (size_t)r0 * 2048 + 1024 + ka_ + c0 * 8);        \
        uh1 = *(const uint4*)(Ab + (size_t)(r0 + 64) * 2048 + 1024 + ka_ + c0 * 8); \
    }                                                                               \
    ub0 = *(const uint4*)(Bb + (size_t)r0 * 2048 + ka_ + c0 * 8);                   \
    ub1 = *(const uint4*)(Bb + (size_t)(r0 + 64) * 2048 + ka_ + c0 * 8);            \
    uc0 = *(const uint4*)(Bb + (size_t)r0 * 2048 + 1024 + ka_ + c0 * 8);            \
    uc1 = *(const uint4*)(Bb + (size_t)(r0 + 64) * 2048 + 1024 + ka_ + c0 * 8);     \
} while (0)

#define WRITET(bi) do {                                                             \
    if (AF32) {                                                                     \
        _Pragma("unroll")                                                           \
        for (int f = 0; f < 4; f++) {                                               \
            h4 lo_, hi_;                                                            \
            _Pragma("unroll")                                                       \
            for (int j = 0; j < 4; j++) {                                           \
                float v_ = ((const float*)&xa[f])[j];                               \
                _Float16 a_ = (_Float16)v_;                                         \
                lo_[j] = a_;                                                        \
                hi_[j] = (_Float16)((v_ - (float)a_) * 4096.0f);                    \
            }                                                                       \
            *(h4*)(&lds[bi][0][0] + (rb + f * 32) * 32 + c4 * 4) = lo_;             \
            *(h4*)(&lds[bi][1][0] + (rb + f * 32) * 32 + c4 * 4) = hi_;             \
        }                                                                           \
    } else {                                                                        \
        *(uint4*)(&lds[bi][0][0] + s0) = ua0; *(uint4*)(&lds[bi][0][0] + s1) = ua1; \
        *(uint4*)(&lds[bi][1][0] + s0) = uh0; *(uint4*)(&lds[bi][1][0] + s1) = uh1; \
    }                                                                               \
    *(uint4*)(&lds[bi][2][0] + s0) = ub0; *(uint4*)(&lds[bi][2][0] + s1) = ub1;     \
    *(uint4*)(&lds[bi][3][0] + s0) = uc0; *(uint4*)(&lds[bi][3][0] + s1) = uc1;     \
} while (0)

    // prologue: tile0 -> buf0; tile1 -> regs
    LOADT(0);
    WRITET(0);
    LOADT(1);
    BAR();

    for (int t = 0; t < NT; t++) {
        int cur = t & 1;
        if (t + 1 < NT) WRITET(cur ^ 1);       // regs hold tile t+1
        if (t + 2 < NT) LOADT(t + 2);          // in flight across barrier
        const _Float16* L0 = &lds[cur][0][0];
        const _Float16* L1 = &lds[cur][1][0];
        const _Float16* L2 = &lds[cur][2][0];
        const _Float16* L3 = &lds[cur][3][0];
        h8 a1f[4], blf[4], bhf[4], a2f[4];
        #pragma unroll
        for (int mi = 0; mi < 4; mi++) {
            a1f[mi] = *(const h8*)(L0 + (wm * 64 + mi * 16 + lr) * 32 + lk * 8);
            a2f[mi] = *(const h8*)(L1 + (wm * 64 + mi * 16 + lr) * 32 + lk * 8);
        }
        #pragma unroll
        for (int ni = 0; ni < 4; ni++) {
            blf[ni] = *(const h8*)(L2 + (wn * 64 + ni * 16 + lr) * 32 + lk * 8);
            bhf[ni] = *(const h8*)(L3 + (wn * 64 + ni * 16 + lr) * 32 + lk * 8);
        }
        __builtin_amdgcn_s_setprio(1);
        #pragma unroll
        for (int mi = 0; mi < 4; mi++)
            #pragma unroll
            for (int ni = 0; ni < 4; ni++) {
                acc1[mi][ni] = __builtin_amdgcn_mfma_f32_16x16x32_f16(a1f[mi], blf[ni], acc1[mi][ni], 0, 0, 0);
                acc2[mi][ni] = __builtin_amdgcn_mfma_f32_16x16x32_f16(a1f[mi], bhf[ni], acc2[mi][ni], 0, 0, 0);
                acc2[mi][ni] = __builtin_amdgcn_mfma_f32_16x16x32_f16(a2f[mi], blf[ni], acc2[mi][ni], 0, 0, 0);
            }
        __builtin_amdgcn_s_setprio(0);
        BAR();
    }
#undef LOADT
#undef WRITET

    // ---- epilogue: C/D layout col=lane&15, row=(lane>>4)*4+reg ----
    #pragma unroll
    for (int mi = 0; mi < 4; mi++)
        #pragma unroll
        for (int ni = 0; ni < 4; ni++) {
            int n = n0 + wn * 64 + ni * 16 + lr;
            float bn = bias[n];
            #pragma unroll
            for (int j = 0; j < 4; j++) {
                int m = m0 + wm * 64 + mi * 16 + lk * 4 + j;
                float val = acc1[mi][ni][j] + acc2[mi][ni][j] * (1.0f / 4096.0f) + bn;
                if (GELU) val = gelu_exact(val);
                if (OSPLIT) {
                    _Float16* Ch = (_Float16*)Cv;
                    _Float16 lo = (_Float16)val;
                    Ch[(size_t)m * ldc + n] = lo;
                    Ch[(size_t)m * ldc + nhalf + n] = (_Float16)((val - (float)lo) * 4096.0f);
                } else {
                    ((float*)Cv)[(size_t)m * ldc + n] = val;
                }
            }
        }
}

// ---------------------------------------------------------------------------
// attn2: wave-autonomous cross-attention. Each wave: one (b,h,64-token tile).
// lane = expert (scores) AND lane = hd (PV). K rows / V^T rows in registers.
// Writes O directly as fp16 split into os (M x 2048).
// ---------------------------------------------------------------------------
__global__ __launch_bounds__(256) void attn2_kernel(
    const float* __restrict__ kbuf, const float* __restrict__ vtbuf,
    const float* __restrict__ q, _Float16* __restrict__ os) {
    __shared__ __align__(16) float qs[4][64][68];
    __shared__ __align__(16) float ps[4][2][64];
    int tid = threadIdx.x;
    int w = tid >> 6, l = tid & 63;
    int wid = blockIdx.x * 4 + w;
    int b = wid >> 9, h = (wid >> 5) & 15, t0 = (wid & 31) * 64;

    f4 kr[16], vt[16];
    const f4* kp = (const f4*)(kbuf + h * 4096 + l * 64);
    const f4* vp = (const f4*)(vtbuf + h * 4096 + l * 64);
    #pragma unroll
    for (int i = 0; i < 16; i++) { kr[i] = kp[i]; vt[i] = vp[i]; }

    const float* qbase = q + ((size_t)(b * 2048 + t0)) * 1024 + h * 64;
    #pragma unroll
    for (int it = 0; it < 16; it++) {
        int f = it * 64 + l;
        int r = f >> 4, c = f & 15;
        f4 v = *(const f4*)(qbase + (size_t)r * 1024 + c * 4);
        *(f4*)&qs[w][r][c * 4] = v;
    }

    for (int t = 0; t < 64; t++) {
        float s = 0.f;
        #pragma unroll
        for (int i = 0; i < 16; i++) {
            f4 qv = *(const f4*)&qs[w][t][i * 4];
            s = fmaf(qv[0], kr[i][0], s);
            s = fmaf(qv[1], kr[i][1], s);
            s = fmaf(qv[2], kr[i][2], s);
            s = fmaf(qv[3], kr[i][3], s);
        }
        s *= 0.125f;
        float ex = __expf(s);
        float sum = ex;
        #pragma unroll
        for (int off = 32; off; off >>= 1) sum += __shfl_xor(sum, off, 64);
        float p = ex / sum;
        ps[w][t & 1][l] = p;
        float o = 0.f;
        #pragma unroll
        for (int i = 0; i < 16; i++) {
            f4 pv = *(const f4*)&ps[w][t & 1][i * 4];
            o = fmaf(pv[0], vt[i][0], o);
            o = fmaf(pv[1], vt[i][1], o);
            o = fmaf(pv[2], vt[i][2], o);
            o = fmaf(pv[3], vt[i][3], o);
        }
        _Float16 o1 = (_Float16)o;
        _Float16 o2 = (_Float16)((o - (float)o1) * 4096.0f);
        size_t tok = (size_t)(b * 2048 + t0 + t);
        os[tok * 2048 + h * 64 + l] = o1;
        os[tok * 2048 + 1024 + h * 64 + l] = o2;
    }
}

// ---------------------------------------------------------------------------
// gate2: logits(16384x64) = h1s(16384x[256|256]) @ gw2s(64x[256|256])^T + b2
// via 4-product split MFMA (frags straight from global/L2), then fused
// softmax + top-2 + weight normalization. Wave handles 16 tokens.
// ---------------------------------------------------------------------------
__global__ __launch_bounds__(256) void gate2_kernel(
    const _Float16* __restrict__ h1s, const _Float16* __restrict__ w2s,
    const float* __restrict__ b2, float* __restrict__ out) {
    int tid = threadIdx.x;
    int w = tid >> 6, l = tid & 63;
    int lr = l & 15, lk = l >> 4;
    int trow = blockIdx.x * 64 + w * 16;        // wave's 16 tokens

    f4 acc1[4], acc2[4], acc3[4];
    #pragma unroll
    for (int ni = 0; ni < 4; ni++) {
        acc1[ni] = (f4){0.f,0.f,0.f,0.f};
        acc2[ni] = (f4){0.f,0.f,0.f,0.f};
        acc3[ni] = (f4){0.f,0.f,0.f,0.f};
    }
    const _Float16* Arow = h1s + (size_t)(trow + lr) * 512;
    #pragma unroll
    for (int kt = 0; kt < 8; kt++) {
        h8 a1 = *(const h8*)(Arow + kt * 32 + lk * 8);
        h8 a2 = *(const h8*)(Arow + 256 + kt * 32 + lk * 8);
        #pragma unroll
        for (int ni = 0; ni < 4; ni++) {
            const _Float16* Brow = w2s + (size_t)(ni * 16 + lr) * 512;
            h8 b1 = *(const h8*)(Brow + kt * 32 + lk * 8);
            h8 bh = *(const h8*)(Brow + 256 + kt * 32 + lk * 8);
            acc1[ni] = __builtin_amdgcn_mfma_f32_16x16x32_f16(a1, b1, acc1[ni], 0, 0, 0);
            acc2[ni] = __builtin_amdgcn_mfma_f32_16x16x32_f16(a1, bh, acc2[ni], 0, 0, 0);
            acc2[ni] = __builtin_amdgcn_mfma_f32_16x16x32_f16(a2, b1, acc2[ni], 0, 0, 0);
            acc3[ni] = __builtin_amdgcn_mfma_f32_16x16x32_f16(a2, bh, acc3[ni], 0, 0, 0);
        }
    }
    float bcol[4];
    #pragma unroll
    for (int ni = 0; ni < 4; ni++) bcol[ni] = b2[ni * 16 + lr];

    const float c1 = 1.0f / 4096.0f, c2 = 1.0f / 16777216.0f;
    #pragma unroll
    for (int j = 0; j < 4; j++) {
        int tok = trow + lk * 4 + j;
        float lg[4];
        #pragma unroll
        for (int ni = 0; ni < 4; ni++)
            lg[ni] = acc1[ni][j] + acc2[ni][j] * c1 + acc3[ni][j] * c2 + bcol[ni];
        float mx = fmaxf(fmaxf(lg[0], lg[1]), fmaxf(lg[2], lg[3]));
        #pragma unroll
        for (int off = 1; off <= 8; off <<= 1) mx = fmaxf(mx, __shfl_xor(mx, off, 64));
        float pr[4], s = 0.f;
        #pragma unroll
        for (int ni = 0; ni < 4; ni++) { pr[ni] = expf(lg[ni] - mx); s += pr[ni]; }
        #pragma unroll
        for (int off = 1; off <= 8; off <<= 1) s += __shfl_xor(s, off, 64);
        float inv = 1.0f / s;
        float v1 = -1.f, v2 = -1.f; int i1 = 0, i2 = 0;
        #pragma unroll
        for (int ni = 0; ni < 4; ni++) {
            float p = pr[ni] * inv;
            int e = ni * 16 + lr;
            if (p > v1) { v2 = v1; i2 = i1; v1 = p; i1 = e; }
            else if (p > v2) { v2 = p; i2 = e; }
        }
        #pragma unroll
        for (int off = 1; off <= 8; off <<= 1) {
            float u1 = __shfl_xor(v1, off, 64); int k1 = __shfl_xor(i1, off, 64);
            float u2 = __shfl_xor(v2, off, 64); int k2 = __shfl_xor(i2, off, 64);
            if (u1 > v1) {
                if (v1 > u2) { v2 = v1; i2 = i1; } else { v2 = u2; i2 = k2; }
                v1 = u1; i1 = k1;
            } else if (u1 > v2) { v2 = u1; i2 = k1; }
        }
        if (lr == 0) {
            float wsum = v1 + v2 + 1e-8f;
            out[(size_t)tok * 2]     = (float)i1;
            out[(size_t)tok * 2 + 1] = (float)i2;
            out[32768 + (size_t)tok * 2]     = v1 / wsum;
            out[32768 + (size_t)tok * 2 + 1] = v2 / wsum;
        }
    }
}

// ---------------------------------------------------------------------------
extern "C" void kernel_launch(void* const* d_in, const int* in_sizes, int n_in,
                              void* d_out, int out_size, void* d_ws, size_t ws_size,
                              hipStream_t stream) {
    const float* x   = (const float*)d_in[0];
    const float* ee  = (const float*)d_in[1];
    const float* ipw = (const float*)d_in[2];
    const float* ipb = (const float*)d_in[3];
    const float* opw = (const float*)d_in[4];
    const float* opb = (const float*)d_in[5];
    const float* gw1 = (const float*)d_in[6];
    const float* gb1 = (const float*)d_in[7];
    const float* gw2 = (const float*)d_in[8];
    const float* gb2 = (const float*)d_in[9];
    float* out = (float*)d_out;
    char* ws = (char*)d_ws;

    // region1 (64MB): os (O-split from attn) -> h1s (h1-split, 16MB)
    _Float16* os    = (_Float16*)ws;                          // 16384 x 2048 fp16
    _Float16* h1s   = (_Float16*)ws;                          // 16384 x 512 fp16 (alias)
    // region2 (64MB): qbuf (Q fp32) -> aos (attn_out split fp16)
    float*    qbuf  = (float*)(ws + 67108864);                // 16384 x 1024 f32
    _Float16* aos   = (_Float16*)(ws + 67108864);             // 16384 x 2048 fp16 (alias)
    _Float16* wqs   = (_Float16*)(ws + 134217728);            // 1024 x 2048
    _Float16* opws  = (_Float16*)(ws + 138412032);            // 1024 x 2048
    _Float16* gw1s  = (_Float16*)(ws + 142606336);            // 256 x 2048
    float*    kbuf  = (float*)(ws + 143654912);               // 16x64x64 f32
    _Float16* gw2s  = (_Float16*)(ws + 143654912);            // 64 x 512 (aliases kbuf, used after attn)
    float*    vtbuf = (float*)(ws + 143917056);               // 16x64x64 f32 (transposed)

    split2_kernel<<<dim3(1024), dim3(256), 0, stream>>>(ipw, wqs, 1048576L, 10);
    split2_kernel<<<dim3(1024), dim3(256), 0, stream>>>(opw, opws, 1048576L, 10);
    split2_kernel<<<dim3(256),  dim3(256), 0, stream>>>(gw1, gw1s, 262144L, 10);
    kv_kernel<<<dim3(32), dim3(256), 0, stream>>>(ipw, ipb, ee, kbuf, vtbuf);
    // Q = x @ wq^T + bq (fp32 A staged+split in-kernel, fp32 out)
    hgemm_kernel<0,0,1><<<dim3(8, 128), dim3(256), 0, stream>>>(x, wqs, ipb, qbuf, 1024, 0);
    // attention; writes split O into region1
    attn2_kernel<<<dim3(1024), dim3(256), 0, stream>>>(kbuf, vtbuf, qbuf, os);
    // gw2 split (aliases kbuf region; kbuf dead after attn2)
    split2_kernel<<<dim3(16), dim3(256), 0, stream>>>(gw2, gw2s, 16384L, 8);
    // attn_out = O @ opw^T + opb -> split fp16 directly (into region2)
    hgemm_kernel<0,1,0><<<dim3(8, 128), dim3(256), 0, stream>>>(os, opws, opb, (void*)aos, 2048, 1024);
    // h1 = gelu(attn_out @ gw1^T + gb1) -> split fp16 (into region1)
    hgemm_kernel<1,1,0><<<dim3(2, 128), dim3(256), 0, stream>>>(aos, gw1s, gb1, (void*)h1s, 512, 256);
    // gate2 + softmax + top2
    gate2_kernel<<<dim3(256), dim3(256), 0, stream>>>(h1s, gw2s, gb2, out);
}